// Round 1
// 58.271 us; speedup vs baseline: 1.0008x; 1.0008x over previous
//
#include <hip/hip_runtime.h>

// SpanRepLayer: start / inner-maxpool / end span reps.
// B=2, NS=512, S=1024, H=128. Output (B, NS, 3H) f32.
//
// R4: occupancy push. The timed iteration is dominated by a fixed ~41us
// 256MiB harness poison fill; the kernel residual is latency-bound (two
// serialized cold-HBM rounds at 0.5 waves/SIMD). Go scalar-per-thread:
// 131072 threads -> 2048 blocks -> 8 blocks/CU (2 waves/SIMD, 4x prior TLP).
// A wave covers 64 consecutive h of ONE span, so gathers stay perfectly
// coalesced (256B/row) and sp is wave-uniform -> ids/masks go through
// readfirstlane onto the scalar (SMEM) path, off the vector memory pipe.
// Still fully branchless: 16 always-executed clamped gathers in one vmcnt
// batch, mask applied as a float multiply.

#define B_  2
#define NS_ 512
#define S_  1024
#define H_  128

__global__ __launch_bounds__(64) void span_rep_kernel(
    const float* __restrict__ tr,    // (B, S, H)
    const int2*  __restrict__ ids,   // (B*NS) [start, end+1]
    const int*   __restrict__ masks, // (B*NS) 0/1
    float*       __restrict__ out)   // (B*NS, 3, H)
{
    int i  = blockIdx.x * 64 + threadIdx.x;   // [0, B*NS*H)
    int sp = i >> 7;          // span index (B*NS) -- uniform across the wave
    int h  = i & (H_ - 1);    // element within H

    // sp is wave-uniform (64 | 128): force the scalar path so ids/masks
    // become s_load (separate SMEM pipe + constant cache).
    int sp_u = __builtin_amdgcn_readfirstlane(sp);

    // Round 1: both small loads issue together on the scalar pipe.
    int2 se = ids[sp_u];
    int  mk = masks[sp_u];

    int start = se.x;
    int end   = se.y - 1;          // inclusive end
    int b     = sp_u >> 9;         // sp / NS_

    const float* base = tr + (size_t)(b * S_ * H_) + h;

    // Inner window [start+1, end-1]; hi clamped so indices stay valid even
    // when no inner region exists (start+1 <= S-1 always, since start <= S-17).
    int lo = start + 1;
    int hi = end - 1;
    hi = hi < lo ? lo : hi;
    bool has_inner = (end - start) >= 2;

    // Round 2: 16 independent gathers, one vmcnt batch.
    float sv = base[start * H_];
    float ev = base[end   * H_];
    float m  = base[lo    * H_];
    #pragma unroll
    for (int t = 2; t <= 14; ++t) {    // inner length <= 14 (MAX_W=16)
        int idx = start + t;
        idx = idx > hi ? hi : idx;     // duplicate loads don't change max
        m = fmaxf(m, base[idx * H_]);
    }

    float iv = has_inner ? m : sv;

    float f = (float)mk;               // 0.0 or 1.0
    float* o = out + (size_t)sp * (3 * H_);
    o[h]          = sv * f;
    o[H_ + h]     = iv * f;
    o[2 * H_ + h] = ev * f;
}

extern "C" void kernel_launch(void* const* d_in, const int* in_sizes, int n_in,
                              void* d_out, int out_size, void* d_ws, size_t ws_size,
                              hipStream_t stream) {
    const float* tr    = (const float*)d_in[0];
    const int2*  ids   = (const int2*)d_in[1];
    const int*   masks = (const int*)d_in[2];
    float*       out   = (float*)d_out;

    const int total = B_ * NS_ * H_;            // 131072 threads
    const int block = 64;
    const int grid  = total / block;            // 2048 blocks -> 8 blocks/CU
    span_rep_kernel<<<grid, block, 0, stream>>>(tr, ids, masks, out);
}